// Round 8
// baseline (146.907 us; speedup 1.0000x reference)
//
#include <hip/hip_runtime.h>
#include <stdint.h>

// Problem constants
#define N_B   32
#define C_INN 8
#define L_IN  4096
#define C_LAT 64
#define K_EMB 512
#define E_DIM 64
#define L_OUT 2049                 // (4096 + 2*2 - 4)/2 + 1
#define M_ROWS (N_B * L_OUT)       // 65568

// d_out layout (flat float32, reference return order)
#define SZ_XREC (N_B * C_INN * L_IN)     // 1048576
#define SZ_ZE   (N_B * C_LAT * L_OUT)    // 4196352
#define OFF_XREC 0
#define OFF_ZE   (SZ_XREC)
#define OFF_ZQ   (OFF_ZE + SZ_ZE)
#define OFF_IDX  (OFF_ZQ + SZ_ZE)

typedef short short8 __attribute__((ext_vector_type(8)));
typedef float f32x4  __attribute__((ext_vector_type(4)));

__device__ __forceinline__ unsigned short rne16(float f) {
    unsigned u = __float_as_uint(f);
    return (unsigned short)((u + 0x7FFFu + ((u >> 16) & 1u)) >> 16);
}
__device__ __forceinline__ float frombits16(unsigned short h) {
    return __uint_as_float(((unsigned)h) << 16);
}
// order-preserving float->u32 (monotone for all finite values)
__device__ __forceinline__ unsigned orderbits(float f) {
    unsigned u = __float_as_uint(f);
    return u ^ ((unsigned)((int)u >> 31) | 0x80000000u);
}

// ---------------------------------------------------------------------------
// Prep: (a) swizzle codebook into MFMA B-fragment order, split bf16 hi/lo;
// (b) 0.5*||c||^2 per code (same float4 summation order everywhere).
// B8 layout (short8 units): idx = ntile*256 + ks*128 + hl*64 + lane.
// ---------------------------------------------------------------------------
__global__ __launch_bounds__(256) void prep_kernel(
    const float* __restrict__ cb, unsigned short* __restrict__ frag,
    float* __restrict__ cbh)
{
    const int ntile = blockIdx.x;        // 0..31
    const int t     = threadIdx.x;
    const int lane  = t & 63;
    const int ks    = (t >> 6) & 1;
    const int h     = t >> 7;            // 0 = hi, 1 = lo
    const int code  = ntile * 16 + (lane & 15);
    const int k0    = ks * 32 + (lane >> 4) * 8;

    const float* src = cb + (size_t)code * E_DIM + k0;
    unsigned short out[8];
#pragma unroll
    for (int j = 0; j < 8; ++j) {
        const float v = src[j];
        const unsigned short hb = rne16(v);
        out[j] = h ? rne16(v - frombits16(hb)) : hb;
    }
    short8 v8;
#pragma unroll
    for (int j = 0; j < 8; ++j) v8[j] = (short)out[j];
    short8* dst = (short8*)(frag + (((size_t)(ntile * 2 + ks) * 2 + h) * 512 + lane * 8));
    *dst = v8;

    if (t < 16) {
        const int c2 = ntile * 16 + t;
        const float4* cp = (const float4*)(cb + (size_t)c2 * E_DIM);
        float s = 0.0f;
#pragma unroll
        for (int d = 0; d < E_DIM / 4; ++d) {
            float4 v = cp[d];
            s += v.x * v.x + v.y * v.y + v.z * v.z + v.w * v.w;
        }
        cbh[c2] = 0.5f * s;
    }
}

// ---------------------------------------------------------------------------
// Fused encode+quantize+decode, round 17. Base = R7 (passing).
// R7 post-mortem: tail-guard + deferred z_e = neutral; residual (total -
// quantize) is 78.7us ROCK-STABLE across rounds and contains decode (R6's
// decode rewrite moved it +9us). This round eliminates the decode kernel:
//  - Phase A epilogue: stash selected z_q rows into LDS (s_cand reused as
//    float[64][69]; dead after compact scan) + one cheap barrier (only LDS
//    writes pending).
//  - Phase B (no barrier after): z_e/z_q/idx stores + fused ConvTranspose
//    for s=tt (rows 0..62, tt<2048): 64ci x 8fma from s_zq[row], s_zq[row+1],
//    coalesced float2 x_rec writes. Same per-ci fma order as old decode.
//  - Boundary rows (row==63, next block owns row+1) -> tiny fixup kernel.
// Decomposition logic: if total barely moves, residual = launch/harness
// fixed cost -> structural floor reached.
// ---------------------------------------------------------------------------
__global__ __launch_bounds__(256, 3) void quantize_kernel(
    const float* __restrict__ x, const float* __restrict__ conv_w,
    const float* __restrict__ conv_b, const float* __restrict__ cb,
    const unsigned short* __restrict__ frag, const float* __restrict__ cbh_ws,
    const float* __restrict__ tconv_w, const float* __restrict__ tconv_b,
    float* __restrict__ z_e, float* __restrict__ z_q,
    float* __restrict__ idx_out, float* __restrict__ x_rec)
{
    __shared__ float s_z[E_DIM][66];         // [chan][row] pad2   (16.9 KB)
    __shared__ float s_cbh[K_EMB];           //                    (2 KB)
    __shared__ unsigned s_cand[64][69];      // 64 slots, odd stride (17.7 KB)
    __shared__ float s_znorm[64];            // 0.5||z||^2 + 1
    __shared__ unsigned s_mstar[64];         // trunc approx-min bits
    __shared__ unsigned long long s_final[64];
    __shared__ unsigned s_list[256];         // compact rescore list (1 KB)
    __shared__ int s_cnt;

    const int tid  = threadIdx.x;
    const int wave = tid >> 6;
    const int lane = tid & 63;
    const int p    = wave >> 1;              // rows 32p..32p+31
    const int h    = wave & 1;               // tiles h*16..h*16+15

    // wave-uniform: does this wave's 32-row strip contain any active row?
    const bool strip_active = (blockIdx.x * 64 + p * 32) < M_ROWS;

    s_cbh[tid]       = cbh_ws[tid];
    s_cbh[tid + 256] = cbh_ws[tid + 256];
    if (tid < 64) s_final[tid] = ~0ULL;
    if (tid == 0) s_cnt = 0;

    // ---- Phase 1: encode my row's 16 channels (row = lane, chans wave*16+j) ----
    const int  row    = tid & 63;
    const int  r      = blockIdx.x * 64 + row;
    const bool active = (r < M_ROWS);
    const unsigned rr = active ? (unsigned)r : 0u;
    const unsigned n  = rr / 2049u;
    const unsigned tt = rr - n * 2049u;

    {
        const float* xrow = x + (size_t)n * (C_INN * L_IN);
        float xv[C_INN][4];
        const bool fast = (tt >= 1 && tt <= 2047);
        if (fast) {
#pragma unroll
            for (int ci = 0; ci < C_INN; ++ci) {
                float4 v = *(const float4*)(xrow + ci * L_IN + (2 * (int)tt - 2));
                xv[ci][0] = v.x; xv[ci][1] = v.y; xv[ci][2] = v.z; xv[ci][3] = v.w;
            }
        } else {
#pragma unroll
            for (int ci = 0; ci < C_INN; ++ci) {
#pragma unroll
                for (int k = 0; k < 4; ++k) {
                    int xi = 2 * (int)tt - 2 + k;
                    int xc = min(max(xi, 0), L_IN - 1);
                    float v = xrow[ci * L_IN + xc];
                    xv[ci][k] = (xi >= 0 && xi < L_IN) ? v : 0.0f;
                }
            }
        }
#pragma unroll
        for (int j = 0; j < 16; ++j) {
            const int c = wave * 16 + j;             // wave-uniform channel
            float a = conv_b[c];
#pragma unroll
            for (int ci = 0; ci < C_INN; ++ci) {
                const float* wp = conv_w + (c * C_INN + ci) * 4;  // uniform
#pragma unroll
                for (int k = 0; k < 4; ++k) a += xv[ci][k] * wp[k];
            }
            s_z[c][row] = a;                         // z_e store deferred
        }
    }
    __syncthreads();

    // ---- row norms (one thread per row) + negated A-fragments (all threads) ----
    if (tid < 64) {
        float s = 0.0f;
#pragma unroll 8
        for (int c = 0; c < E_DIM; ++c) {
            const float v = s_z[c][tid];
            s += v * v;
        }
        s_znorm[tid] = 0.5f * s + 1.0f;
    }

    const int m = lane & 15, q = lane >> 4;
    short8 Ah[2][2], Al[2][2];               // [strip][ks], A = -z
    if (strip_active) {
#pragma unroll
        for (int st = 0; st < 2; ++st) {
            const int arow = p * 32 + st * 16 + m;
#pragma unroll
            for (int ks = 0; ks < 2; ++ks) {
#pragma unroll
                for (int j = 0; j < 8; ++j) {
                    const float v = -s_z[ks * 32 + q * 8 + j][arow];
                    const unsigned short hb = rne16(v);
                    Ah[st][ks][j] = (short)hb;
                    Al[st][ks][j] = (short)rne16(v - frombits16(hb));
                }
            }
        }
    }
    __syncthreads();

    float Kn[2][4];
#pragma unroll
    for (int st = 0; st < 2; ++st)
#pragma unroll
        for (int r4 = 0; r4 < 4; ++r4)
            Kn[st][r4] = s_znorm[p * 32 + st * 16 + q * 4 + r4];

    // ---- screen: 16 tiles of half h, register prefetch depth 1 ----
    unsigned ca[2][4], cb2[2][4];
#pragma unroll
    for (int st = 0; st < 2; ++st)
#pragma unroll
        for (int r4 = 0; r4 < 4; ++r4) { ca[st][r4] = 0xFFFFFFFFu; cb2[st][r4] = 0xFFFFFFFFu; }

    if (strip_active) {
        const short8* B8 = (const short8*)frag;
        short8 Bc[4], Bn[4];
        {
            const int base = (h * 16) * 256 + lane;
#pragma unroll
            for (int v = 0; v < 4; ++v) Bc[v] = B8[base + v * 64];
        }

        for (int t = 0; t < 16; ++t) {
            if (t < 15) {
                const int base = (h * 16 + t + 1) * 256 + lane;
#pragma unroll
                for (int v = 0; v < 4; ++v) Bn[v] = B8[base + v * 64];
            }
            const int code = (h * 16 + t) * 16 + m;
            const float chv = s_cbh[code];

            f32x4 accA = {chv + Kn[0][0], chv + Kn[0][1], chv + Kn[0][2], chv + Kn[0][3]};
            f32x4 accB = {chv + Kn[1][0], chv + Kn[1][1], chv + Kn[1][2], chv + Kn[1][3]};
            accA = __builtin_amdgcn_mfma_f32_16x16x32_bf16(Ah[0][0], Bc[0], accA, 0, 0, 0);
            accB = __builtin_amdgcn_mfma_f32_16x16x32_bf16(Ah[1][0], Bc[0], accB, 0, 0, 0);
            accA = __builtin_amdgcn_mfma_f32_16x16x32_bf16(Ah[0][0], Bc[1], accA, 0, 0, 0);
            accB = __builtin_amdgcn_mfma_f32_16x16x32_bf16(Ah[1][0], Bc[1], accB, 0, 0, 0);
            accA = __builtin_amdgcn_mfma_f32_16x16x32_bf16(Al[0][0], Bc[0], accA, 0, 0, 0);
            accB = __builtin_amdgcn_mfma_f32_16x16x32_bf16(Al[1][0], Bc[0], accB, 0, 0, 0);
            accA = __builtin_amdgcn_mfma_f32_16x16x32_bf16(Ah[0][1], Bc[2], accA, 0, 0, 0);
            accB = __builtin_amdgcn_mfma_f32_16x16x32_bf16(Ah[1][1], Bc[2], accB, 0, 0, 0);
            accA = __builtin_amdgcn_mfma_f32_16x16x32_bf16(Ah[0][1], Bc[3], accA, 0, 0, 0);
            accB = __builtin_amdgcn_mfma_f32_16x16x32_bf16(Ah[1][1], Bc[3], accB, 0, 0, 0);
            accA = __builtin_amdgcn_mfma_f32_16x16x32_bf16(Al[0][1], Bc[2], accA, 0, 0, 0);
            accB = __builtin_amdgcn_mfma_f32_16x16x32_bf16(Al[1][1], Bc[2], accB, 0, 0, 0);

#pragma unroll
            for (int st = 0; st < 2; ++st) {
                const f32x4 acc = st ? accB : accA;
#pragma unroll
                for (int r4 = 0; r4 < 4; ++r4) {
                    const unsigned xx = (__float_as_uint(acc[r4]) & 0xFFFFFFF0u) | (unsigned)t;
                    const unsigned mx = max(ca[st][r4], xx);
                    ca[st][r4]  = min(ca[st][r4], xx);
                    cb2[st][r4] = min(cb2[st][r4], mx);
                }
            }
#pragma unroll
            for (int v = 0; v < 4; ++v) Bc[v] = Bn[v];
        }
    }

    // deposit: row = 32p + 16st + 4q + r4, slots h*32 + 2m (+1)
#pragma unroll
    for (int st = 0; st < 2; ++st)
#pragma unroll
        for (int r4 = 0; r4 < 4; ++r4) {
            const int rw = p * 32 + st * 16 + q * 4 + r4;
            s_cand[rw][h * 32 + 2 * m + 0] = ca[st][r4];
            s_cand[rw][h * 32 + 2 * m + 1] = cb2[st][r4];
        }
    __syncthreads();

    // per-row approx min over the 64 candidate slots
    if (tid < 64) {
        unsigned mn = 0xFFFFFFFFu;
#pragma unroll 8
        for (int i = 0; i < 64; ++i) mn = min(mn, s_cand[tid][i]);
        s_mstar[tid] = mn & 0xFFFFFFF0u;
    }
    __syncthreads();

    // ---- compact: scan candidates within m* + eps into s_list (cheap) ----
    {
        const int rw  = tid >> 2;                    // 4 threads per row
        const float thr = __uint_as_float(s_mstar[rw]) + 0.02f;
#pragma unroll
        for (int j = 0; j < 16; ++j) {
            const int sl = (tid & 3) * 16 + j;       // 0..63
            const unsigned cand = s_cand[rw][sl];
            const float fd = __uint_as_float(cand & 0xFFFFFFF0u);
            if (fd <= thr) {
                // slot -> (half = sl>>5, class m = (sl>>1)&15), tile = cand&15
                const unsigned code =
                    (((unsigned)(sl >> 5) * 16u + (cand & 15u)) * 16u) +
                    (unsigned)((sl >> 1) & 15);
                const int pos = atomicAdd(&s_cnt, 1);
                if (pos < 256) {
                    s_list[pos] = ((unsigned)rw << 9) | code;
                } else {
                    // overflow fallback (practically never): old inline exact path
                    const float4* c4 = (const float4*)(cb + (size_t)code * E_DIM);
                    float dot = 0.0f;
#pragma unroll
                    for (int d4 = 0; d4 < 16; ++d4) {
                        const float4 cv = c4[d4];
                        dot += s_z[d4 * 4 + 0][rw] * cv.x +
                               s_z[d4 * 4 + 1][rw] * cv.y +
                               s_z[d4 * 4 + 2][rw] * cv.z +
                               s_z[d4 * 4 + 3][rw] * cv.w;
                    }
                    const float mex = s_cbh[code] - dot;
                    const unsigned long long px =
                        ((unsigned long long)orderbits(mex) << 32) | code;
                    atomicMin(&s_final[rw], px);
                }
            }
        }
    }
    __syncthreads();

    // ---- dense rescore: one entry per lane, single pass ----
    {
        const int nk = min(s_cnt, 256);
        for (int e = tid; e < nk; e += 256) {
            const unsigned ent = s_list[e];
            const int rw = (int)(ent >> 9);
            const unsigned code = ent & 511u;
            const float4* c4 = (const float4*)(cb + (size_t)code * E_DIM);
            float dot = 0.0f;
#pragma unroll
            for (int d4 = 0; d4 < 16; ++d4) {
                const float4 cv = c4[d4];
                dot += s_z[d4 * 4 + 0][rw] * cv.x +
                       s_z[d4 * 4 + 1][rw] * cv.y +
                       s_z[d4 * 4 + 2][rw] * cv.z +
                       s_z[d4 * 4 + 3][rw] * cv.w;
            }
            const float mex = s_cbh[code] - dot;
            const unsigned long long px =
                ((unsigned long long)orderbits(mex) << 32) | code;
            atomicMin(&s_final[rw], px);
        }
    }
    __syncthreads();

    // ---- Phase A: gather selected codebook row; stash into LDS for decode.
    // s_cand is dead past this point -> reuse as float z_q cache [64][69].
    float* s_zq = (float*)&s_cand[0][0];     // stride 69, 2-way-free banks
    unsigned fk = 0;
    float4 csel4[4];
    if (active) {
        fk = (unsigned)s_final[row];
        const float4* csel = (const float4*)(cb + (size_t)fk * E_DIM);
#pragma unroll
        for (int j4 = 0; j4 < 4; ++j4) csel4[j4] = csel[wave * 4 + j4];
#pragma unroll
        for (int j4 = 0; j4 < 4; ++j4) {
            const int c = wave * 16 + j4 * 4;       // chans wave*16+4j4..+3
            s_zq[row * 69 + c + 0] = csel4[j4].x;
            s_zq[row * 69 + c + 1] = csel4[j4].y;
            s_zq[row * 69 + c + 2] = csel4[j4].z;
            s_zq[row * 69 + c + 3] = csel4[j4].w;
        }
    }
    __syncthreads();   // only LDS writes pending -> cheap drain

    // ---- Phase B: all global stores + fused decode; no barrier after ----
    if (active) {
        float* zez = z_e + (size_t)n * (C_LAT * L_OUT) + tt;
        float* zq  = z_q + (size_t)n * (C_LAT * L_OUT) + tt;
#pragma unroll
        for (int j = 0; j < 16; ++j) {
            const int c = wave * 16 + j;
            zez[(size_t)c * L_OUT] = s_z[c][row];
        }
#pragma unroll
        for (int j4 = 0; j4 < 4; ++j4) {
            const int c = wave * 16 + j4 * 4;
            zq[(size_t)(c + 0) * L_OUT] = csel4[j4].x;
            zq[(size_t)(c + 1) * L_OUT] = csel4[j4].y;
            zq[(size_t)(c + 2) * L_OUT] = csel4[j4].z;
            zq[(size_t)(c + 3) * L_OUT] = csel4[j4].w;
        }
        if (tid < 64) idx_out[r] = (float)fk;

        // fused ConvTranspose for s = tt (this wave handles co = wave*2, +1).
        // Needs row+1's z_q: in-block only for row < 63 (row 63 -> fixup).
        if (row < 63 && tt < 2048) {
            const int co0 = wave * 2;
            float e0 = tconv_b[co0],     o0 = e0;
            float e1 = tconv_b[co0 + 1], o1 = e1;
            const float* z0p = s_zq + row * 69;
            const float* z1p = s_zq + (row + 1) * 69;
#pragma unroll 8
            for (int ci = 0; ci < C_LAT; ++ci) {
                const float z0 = z0p[ci];
                const float z1 = z1p[ci];
                const float* wp = tconv_w + (ci * C_INN + co0) * 4;  // uniform
                e0 += z0 * wp[2] + z1 * wp[0];
                o0 += z0 * wp[3] + z1 * wp[1];
                e1 += z0 * wp[6] + z1 * wp[4];
                o1 += z0 * wp[7] + z1 * wp[5];
            }
            float* xr0 = x_rec + ((size_t)(n * C_INN + co0)) * L_IN + 2 * tt;
            float* xr1 = x_rec + ((size_t)(n * C_INN + co0 + 1)) * L_IN + 2 * tt;
            *(float2*)xr0 = make_float2(e0, o0);
            *(float2*)xr1 = make_float2(e1, o1);
        }
    }
}

// ---------------------------------------------------------------------------
// Boundary fixup: output columns s = tt for rows r = 64b + 63 (the in-block
// fused decode cannot see row+1 across blocks). 1024 boundaries; skip
// tt == 2048 (no output column). Same per-ci fma order as the fused path.
// ---------------------------------------------------------------------------
__global__ __launch_bounds__(64) void fixup_kernel(
    const float* __restrict__ zq, const float* __restrict__ w,
    const float* __restrict__ b, float* __restrict__ xr)
{
    const int bd = blockIdx.x;              // 0..1023
    const int r  = bd * 64 + 63;
    const unsigned n  = (unsigned)r / 2049u;
    const unsigned tt = (unsigned)r - n * 2049u;
    if (tt >= 2048) return;                 // block-uniform exit

    __shared__ float zz[2][64];
    const int ci = threadIdx.x;             // 0..63
    const float* zp = zq + (size_t)n * (C_LAT * L_OUT) + (size_t)ci * L_OUT + tt;
    zz[0][ci] = zp[0];
    zz[1][ci] = zp[1];
    __syncthreads();

    if (ci < 16) {
        const int co = ci >> 1, par = ci & 1;
        float a = b[co];
        for (int c = 0; c < C_LAT; ++c) {
            const float* wp = w + (c * C_INN + co) * 4;
            a += zz[0][c] * wp[2 + par] + zz[1][c] * wp[0 + par];
        }
        xr[((size_t)(n * C_INN + co)) * L_IN + 2 * tt + par] = a;
    }
}

// ---------------------------------------------------------------------------
extern "C" void kernel_launch(void* const* d_in, const int* in_sizes, int n_in,
                              void* d_out, int out_size, void* d_ws, size_t ws_size,
                              hipStream_t stream) {
    const float* x        = (const float*)d_in[0];
    const float* conv_w   = (const float*)d_in[1];
    const float* conv_b   = (const float*)d_in[2];
    const float* codebook = (const float*)d_in[3];
    const float* tconv_w  = (const float*)d_in[4];
    const float* tconv_b  = (const float*)d_in[5];

    float* out   = (float*)d_out;
    float* x_rec = out + OFF_XREC;
    float* z_e   = out + OFF_ZE;
    float* z_q   = out + OFF_ZQ;
    float* idxs  = out + OFF_IDX;

    unsigned short* frag = (unsigned short*)d_ws;        // 131072 B
    float*          cbh  = (float*)(frag + 65536);       // + 2048 B

    prep_kernel<<<32, 256, 0, stream>>>(codebook, frag, cbh);
    quantize_kernel<<<(M_ROWS + 63) / 64, 256, 0, stream>>>(
        x, conv_w, conv_b, codebook, frag, cbh, tconv_w, tconv_b,
        z_e, z_q, idxs, x_rec);
    fixup_kernel<<<1024, 64, 0, stream>>>(z_q, tconv_w, tconv_b, x_rec);
}

// Round 9
// 120.191 us; speedup vs baseline: 1.2223x; 1.2223x over previous
//
#include <hip/hip_runtime.h>
#include <stdint.h>

// Problem constants
#define N_B   32
#define C_INN 8
#define L_IN  4096
#define C_LAT 64
#define K_EMB 512
#define E_DIM 64
#define L_OUT 2049                 // (4096 + 2*2 - 4)/2 + 1
#define M_ROWS (N_B * L_OUT)       // 65568

// d_out layout (flat float32, reference return order)
#define SZ_XREC (N_B * C_INN * L_IN)     // 1048576
#define SZ_ZE   (N_B * C_LAT * L_OUT)    // 4196352
#define OFF_XREC 0
#define OFF_ZE   (SZ_XREC)
#define OFF_ZQ   (OFF_ZE + SZ_ZE)
#define OFF_IDX  (OFF_ZQ + SZ_ZE)

typedef short short8 __attribute__((ext_vector_type(8)));
typedef float f32x4  __attribute__((ext_vector_type(4)));

__device__ __forceinline__ unsigned short rne16(float f) {
    unsigned u = __float_as_uint(f);
    return (unsigned short)((u + 0x7FFFu + ((u >> 16) & 1u)) >> 16);
}
__device__ __forceinline__ float frombits16(unsigned short h) {
    return __uint_as_float(((unsigned)h) << 16);
}
// order-preserving float->u32 (monotone for all finite values)
__device__ __forceinline__ unsigned orderbits(float f) {
    unsigned u = __float_as_uint(f);
    return u ^ ((unsigned)((int)u >> 31) | 0x80000000u);
}

// ---------------------------------------------------------------------------
// Prep: (a) swizzle codebook into MFMA B-fragment order, split bf16 hi/lo;
// (b) 0.5*||c||^2 per code (same float4 summation order everywhere).
// B8 layout (short8 units): idx = ntile*256 + ks*128 + hl*64 + lane.
// ---------------------------------------------------------------------------
__global__ __launch_bounds__(256) void prep_kernel(
    const float* __restrict__ cb, unsigned short* __restrict__ frag,
    float* __restrict__ cbh)
{
    const int ntile = blockIdx.x;        // 0..31
    const int t     = threadIdx.x;
    const int lane  = t & 63;
    const int ks    = (t >> 6) & 1;
    const int h     = t >> 7;            // 0 = hi, 1 = lo
    const int code  = ntile * 16 + (lane & 15);
    const int k0    = ks * 32 + (lane >> 4) * 8;

    const float* src = cb + (size_t)code * E_DIM + k0;
    unsigned short out[8];
#pragma unroll
    for (int j = 0; j < 8; ++j) {
        const float v = src[j];
        const unsigned short hb = rne16(v);
        out[j] = h ? rne16(v - frombits16(hb)) : hb;
    }
    short8 v8;
#pragma unroll
    for (int j = 0; j < 8; ++j) v8[j] = (short)out[j];
    short8* dst = (short8*)(frag + (((size_t)(ntile * 2 + ks) * 2 + h) * 512 + lane * 8));
    *dst = v8;

    if (t < 16) {
        const int c2 = ntile * 16 + t;
        const float4* cp = (const float4*)(cb + (size_t)c2 * E_DIM);
        float s = 0.0f;
#pragma unroll
        for (int d = 0; d < E_DIM / 4; ++d) {
            float4 v = cp[d];
            s += v.x * v.x + v.y * v.y + v.z * v.z + v.w * v.w;
        }
        cbh[c2] = 0.5f * s;
    }
}

// ---------------------------------------------------------------------------
// Fused encode+quantize, round 18 = R1 structure (session best, 131.1us)
// + the R8 lesson applied in reverse:
//  (1) wb = readfirstlane(wave) for ALL wave-derived indices. R8 proved
//      non-provable uniformity costs hundreds of per-lane VMEM loads; here
//      it converts encode's 128 conv_w dwordx4 loads/thread into s_loads
//      and scalar-folds B8/epilogue addressing.
//  (2) row-norm partials s_pn[row][wb] accumulated during encode; the
//      tid<64 norm phase sums 4 values instead of 64 LDS reads. znorm
//      epsilon shifts all of a row's candidates equally -> ordering,
//      window, exact rescore unaffected.
//  (3) s_cand stride 69 (conflict-free min-scan; free).
// R7's strip_active / deferred-z_e dropped (measured neutral, +16 VGPR).
// R4/R5 lesson: (256,3); natural footprint 64 arch + 64 acc VGPR; never
// force 8 waves/SIMD (spills to HBM).
// Decomposition ledger (R8): residual = ~10us decode + ~4us prep + ~65us
// fixed harness/launch cost -> quantize micro-efficiency is the only
// remaining kernel-side lever.
// ---------------------------------------------------------------------------
__global__ __launch_bounds__(256, 3) void quantize_kernel(
    const float* __restrict__ x, const float* __restrict__ conv_w,
    const float* __restrict__ conv_b, const float* __restrict__ cb,
    const unsigned short* __restrict__ frag, const float* __restrict__ cbh_ws,
    float* __restrict__ z_e, float* __restrict__ z_q,
    float* __restrict__ idx_out)
{
    __shared__ float s_z[E_DIM][66];         // [chan][row] pad2   (16.9 KB)
    __shared__ float s_cbh[K_EMB];           //                    (2 KB)
    __shared__ unsigned s_cand[64][69];      // 64 slots, odd stride (17.7 KB)
    __shared__ float s_pn[64][4];            // per-(row,wave) norm partials
    __shared__ float s_znorm[64];            // 0.5||z||^2 + 1
    __shared__ unsigned s_mstar[64];         // trunc approx-min bits
    __shared__ unsigned long long s_final[64];
    __shared__ unsigned s_list[256];         // compact rescore list (1 KB)
    __shared__ int s_cnt;

    const int tid  = threadIdx.x;
    const int wave = tid >> 6;
    const int lane = tid & 63;
    const int wb   = __builtin_amdgcn_readfirstlane(wave); // provably uniform
    const int p    = wb >> 1;                // rows 32p..32p+31
    const int h    = wb & 1;                 // tiles h*16..h*16+15

    s_cbh[tid]       = cbh_ws[tid];
    s_cbh[tid + 256] = cbh_ws[tid + 256];
    if (tid < 64) s_final[tid] = ~0ULL;
    if (tid == 0) s_cnt = 0;

    // ---- Phase 1: encode my row's 16 channels (row = lane, chans wb*16+j) ----
    const int  row    = lane;
    const int  r      = blockIdx.x * 64 + row;
    const bool active = (r < M_ROWS);
    const unsigned rr = active ? (unsigned)r : 0u;
    const unsigned n  = rr / 2049u;
    const unsigned tt = rr - n * 2049u;

    {
        const float* xrow = x + (size_t)n * (C_INN * L_IN);
        float xv[C_INN][4];
        const bool fast = (tt >= 1 && tt <= 2047);
        if (fast) {
#pragma unroll
            for (int ci = 0; ci < C_INN; ++ci) {
                float4 v = *(const float4*)(xrow + ci * L_IN + (2 * (int)tt - 2));
                xv[ci][0] = v.x; xv[ci][1] = v.y; xv[ci][2] = v.z; xv[ci][3] = v.w;
            }
        } else {
#pragma unroll
            for (int ci = 0; ci < C_INN; ++ci) {
#pragma unroll
                for (int k = 0; k < 4; ++k) {
                    int xi = 2 * (int)tt - 2 + k;
                    int xc = min(max(xi, 0), L_IN - 1);
                    float v = xrow[ci * L_IN + xc];
                    xv[ci][k] = (xi >= 0 && xi < L_IN) ? v : 0.0f;
                }
            }
        }
        float* zcol = z_e + (size_t)n * (C_LAT * L_OUT) + tt;
        float pn = 0.0f;
#pragma unroll
        for (int j = 0; j < 16; ++j) {
            const int c = wb * 16 + j;               // SGPR-uniform channel
            float a = conv_b[c];                     // s_load
#pragma unroll
            for (int ci = 0; ci < C_INN; ++ci) {
                const float* wp = conv_w + (c * C_INN + ci) * 4;  // s_load
#pragma unroll
                for (int k = 0; k < 4; ++k) a += xv[ci][k] * wp[k];
            }
            pn += a * a;
            s_z[c][row] = a;
            if (active) zcol[(size_t)c * L_OUT] = a;
        }
        s_pn[row][wb] = pn;
    }
    __syncthreads();

    // ---- row norms from 4 partials (one thread per row) ----
    if (tid < 64) {
        s_znorm[tid] = 0.5f * (s_pn[tid][0] + s_pn[tid][1] +
                               s_pn[tid][2] + s_pn[tid][3]) + 1.0f;
    }

    const int m = lane & 15, q = lane >> 4;
    short8 Ah[2][2], Al[2][2];               // [strip][ks], A = -z
#pragma unroll
    for (int st = 0; st < 2; ++st) {
        const int arow = p * 32 + st * 16 + m;
#pragma unroll
        for (int ks = 0; ks < 2; ++ks) {
#pragma unroll
            for (int j = 0; j < 8; ++j) {
                const float v = -s_z[ks * 32 + q * 8 + j][arow];
                const unsigned short hb = rne16(v);
                Ah[st][ks][j] = (short)hb;
                Al[st][ks][j] = (short)rne16(v - frombits16(hb));
            }
        }
    }
    __syncthreads();

    float Kn[2][4];
#pragma unroll
    for (int st = 0; st < 2; ++st)
#pragma unroll
        for (int r4 = 0; r4 < 4; ++r4)
            Kn[st][r4] = s_znorm[p * 32 + st * 16 + q * 4 + r4];

    // ---- screen: 16 tiles of half h, register prefetch depth 1 ----
    unsigned ca[2][4], cb2[2][4];
#pragma unroll
    for (int st = 0; st < 2; ++st)
#pragma unroll
        for (int r4 = 0; r4 < 4; ++r4) { ca[st][r4] = 0xFFFFFFFFu; cb2[st][r4] = 0xFFFFFFFFu; }

    const short8* B8 = (const short8*)frag;
    short8 Bc[4], Bn[4];
    {
        const int base = (h * 16) * 256 + lane;      // scalar base + lane
#pragma unroll
        for (int v = 0; v < 4; ++v) Bc[v] = B8[base + v * 64];
    }

    for (int t = 0; t < 16; ++t) {
        if (t < 15) {
            const int base = (h * 16 + t + 1) * 256 + lane;
#pragma unroll
            for (int v = 0; v < 4; ++v) Bn[v] = B8[base + v * 64];
        }
        const int code = (h * 16 + t) * 16 + m;
        const float chv = s_cbh[code];

        f32x4 accA = {chv + Kn[0][0], chv + Kn[0][1], chv + Kn[0][2], chv + Kn[0][3]};
        f32x4 accB = {chv + Kn[1][0], chv + Kn[1][1], chv + Kn[1][2], chv + Kn[1][3]};
        accA = __builtin_amdgcn_mfma_f32_16x16x32_bf16(Ah[0][0], Bc[0], accA, 0, 0, 0);
        accB = __builtin_amdgcn_mfma_f32_16x16x32_bf16(Ah[1][0], Bc[0], accB, 0, 0, 0);
        accA = __builtin_amdgcn_mfma_f32_16x16x32_bf16(Ah[0][0], Bc[1], accA, 0, 0, 0);
        accB = __builtin_amdgcn_mfma_f32_16x16x32_bf16(Ah[1][0], Bc[1], accB, 0, 0, 0);
        accA = __builtin_amdgcn_mfma_f32_16x16x32_bf16(Al[0][0], Bc[0], accA, 0, 0, 0);
        accB = __builtin_amdgcn_mfma_f32_16x16x32_bf16(Al[1][0], Bc[0], accB, 0, 0, 0);
        accA = __builtin_amdgcn_mfma_f32_16x16x32_bf16(Ah[0][1], Bc[2], accA, 0, 0, 0);
        accB = __builtin_amdgcn_mfma_f32_16x16x32_bf16(Ah[1][1], Bc[2], accB, 0, 0, 0);
        accA = __builtin_amdgcn_mfma_f32_16x16x32_bf16(Ah[0][1], Bc[3], accA, 0, 0, 0);
        accB = __builtin_amdgcn_mfma_f32_16x16x32_bf16(Ah[1][1], Bc[3], accB, 0, 0, 0);
        accA = __builtin_amdgcn_mfma_f32_16x16x32_bf16(Al[0][1], Bc[2], accA, 0, 0, 0);
        accB = __builtin_amdgcn_mfma_f32_16x16x32_bf16(Al[1][1], Bc[2], accB, 0, 0, 0);

#pragma unroll
        for (int st = 0; st < 2; ++st) {
            const f32x4 acc = st ? accB : accA;
#pragma unroll
            for (int r4 = 0; r4 < 4; ++r4) {
                const unsigned xx = (__float_as_uint(acc[r4]) & 0xFFFFFFF0u) | (unsigned)t;
                const unsigned mx = max(ca[st][r4], xx);
                ca[st][r4]  = min(ca[st][r4], xx);
                cb2[st][r4] = min(cb2[st][r4], mx);
            }
        }
#pragma unroll
        for (int v = 0; v < 4; ++v) Bc[v] = Bn[v];
    }

    // deposit: row = 32p + 16st + 4q + r4, slots h*32 + 2m (+1)
#pragma unroll
    for (int st = 0; st < 2; ++st)
#pragma unroll
        for (int r4 = 0; r4 < 4; ++r4) {
            const int rw = p * 32 + st * 16 + q * 4 + r4;
            s_cand[rw][h * 32 + 2 * m + 0] = ca[st][r4];
            s_cand[rw][h * 32 + 2 * m + 1] = cb2[st][r4];
        }
    __syncthreads();

    // per-row approx min over the 64 candidate slots
    if (tid < 64) {
        unsigned mn = 0xFFFFFFFFu;
#pragma unroll 8
        for (int i = 0; i < 64; ++i) mn = min(mn, s_cand[tid][i]);
        s_mstar[tid] = mn & 0xFFFFFFF0u;
    }
    __syncthreads();

    // ---- compact: scan candidates within m* + eps into s_list (cheap) ----
    {
        const int rw  = tid >> 2;                    // 4 threads per row
        const float thr = __uint_as_float(s_mstar[rw]) + 0.02f;
#pragma unroll
        for (int j = 0; j < 16; ++j) {
            const int sl = (tid & 3) * 16 + j;       // 0..63
            const unsigned cand = s_cand[rw][sl];
            const float fd = __uint_as_float(cand & 0xFFFFFFF0u);
            if (fd <= thr) {
                // slot -> (half = sl>>5, class m = (sl>>1)&15), tile = cand&15
                const unsigned code =
                    (((unsigned)(sl >> 5) * 16u + (cand & 15u)) * 16u) +
                    (unsigned)((sl >> 1) & 15);
                const int pos = atomicAdd(&s_cnt, 1);
                if (pos < 256) {
                    s_list[pos] = ((unsigned)rw << 9) | code;
                } else {
                    // overflow fallback (practically never): inline exact path
                    const float4* c4 = (const float4*)(cb + (size_t)code * E_DIM);
                    float dot = 0.0f;
#pragma unroll
                    for (int d4 = 0; d4 < 16; ++d4) {
                        const float4 cv = c4[d4];
                        dot += s_z[d4 * 4 + 0][rw] * cv.x +
                               s_z[d4 * 4 + 1][rw] * cv.y +
                               s_z[d4 * 4 + 2][rw] * cv.z +
                               s_z[d4 * 4 + 3][rw] * cv.w;
                    }
                    const float mex = s_cbh[code] - dot;
                    const unsigned long long px =
                        ((unsigned long long)orderbits(mex) << 32) | code;
                    atomicMin(&s_final[rw], px);
                }
            }
        }
    }
    __syncthreads();

    // ---- dense rescore: one entry per lane, single pass ----
    {
        const int nk = min(s_cnt, 256);
        for (int e = tid; e < nk; e += 256) {
            const unsigned ent = s_list[e];
            const int rw = (int)(ent >> 9);
            const unsigned code = ent & 511u;
            const float4* c4 = (const float4*)(cb + (size_t)code * E_DIM);
            float dot = 0.0f;
#pragma unroll
            for (int d4 = 0; d4 < 16; ++d4) {
                const float4 cv = c4[d4];
                dot += s_z[d4 * 4 + 0][rw] * cv.x +
                       s_z[d4 * 4 + 1][rw] * cv.y +
                       s_z[d4 * 4 + 2][rw] * cv.z +
                       s_z[d4 * 4 + 3][rw] * cv.w;
            }
            const float mex = s_cbh[code] - dot;
            const unsigned long long px =
                ((unsigned long long)orderbits(mex) << 32) | code;
            atomicMin(&s_final[rw], px);
        }
    }
    __syncthreads();

    // epilogue: z_q gather (4x dwordx4) + coalesced column writes; idx as float
    if (active) {
        const unsigned fk = (unsigned)s_final[row];
        const float4* csel = (const float4*)(cb + (size_t)fk * E_DIM);
        float* zq = z_q + (size_t)n * (C_LAT * L_OUT) + tt;
#pragma unroll
        for (int j4 = 0; j4 < 4; ++j4) {
            const float4 cv = csel[wb * 4 + j4];     // chans wb*16+4j4..+3
            const int c = wb * 16 + j4 * 4;
            zq[(size_t)(c + 0) * L_OUT] = cv.x;
            zq[(size_t)(c + 1) * L_OUT] = cv.y;
            zq[(size_t)(c + 2) * L_OUT] = cv.z;
            zq[(size_t)(c + 3) * L_OUT] = cv.w;
        }
        if (tid < 64) idx_out[r] = (float)fk;
    }
}

// ---------------------------------------------------------------------------
// Decode (ConvTranspose1d) — exact original shape (best measured residual):
// 1024 blocks (n x 2 co-groups x 16 s-chunks) x 128 thr, 4 co per block.
// co0 derives from blockIdx (scalar) -> weight loads are genuine s_loads.
// ---------------------------------------------------------------------------
__global__ __launch_bounds__(128) void decode_kernel(
    const float* __restrict__ zq, const float* __restrict__ w,
    const float* __restrict__ b, float* __restrict__ xr)
{
    const int blk   = blockIdx.x;           // 0..1023
    const int chunk = blk & 15;
    const int cog   = (blk >> 4) & 1;
    const int n     = blk >> 5;
    const int s     = chunk * 128 + threadIdx.x;   // 0..2047
    const int co0   = cog * 4;

    const float* zn = zq + (size_t)n * (C_LAT * L_OUT) + s;
    float e[4], o[4];
#pragma unroll
    for (int j = 0; j < 4; ++j) { e[j] = b[co0 + j]; o[j] = e[j]; }

#pragma unroll 4
    for (int ci = 0; ci < C_LAT; ++ci) {
        const float z0 = zn[(size_t)ci * L_OUT];
        const float z1 = zn[(size_t)ci * L_OUT + 1];
        const float* wp = w + (ci * C_INN + co0) * 4;   // scalar address
#pragma unroll
        for (int j = 0; j < 4; ++j) {
            e[j] += z0 * wp[4 * j + 2] + z1 * wp[4 * j + 0];
            o[j] += z0 * wp[4 * j + 3] + z1 * wp[4 * j + 1];
        }
    }

#pragma unroll
    for (int j = 0; j < 4; ++j) {
        float* xrow = xr + ((size_t)(n * C_INN + co0 + j)) * L_IN;
        *(float2*)(xrow + 2 * s) = make_float2(e[j], o[j]);   // 8B aligned
    }
}

// ---------------------------------------------------------------------------
extern "C" void kernel_launch(void* const* d_in, const int* in_sizes, int n_in,
                              void* d_out, int out_size, void* d_ws, size_t ws_size,
                              hipStream_t stream) {
    const float* x        = (const float*)d_in[0];
    const float* conv_w   = (const float*)d_in[1];
    const float* conv_b   = (const float*)d_in[2];
    const float* codebook = (const float*)d_in[3];
    const float* tconv_w  = (const float*)d_in[4];
    const float* tconv_b  = (const float*)d_in[5];

    float* out   = (float*)d_out;
    float* x_rec = out + OFF_XREC;
    float* z_e   = out + OFF_ZE;
    float* z_q   = out + OFF_ZQ;
    float* idxs  = out + OFF_IDX;

    unsigned short* frag = (unsigned short*)d_ws;        // 131072 B
    float*          cbh  = (float*)(frag + 65536);       // + 2048 B

    prep_kernel<<<32, 256, 0, stream>>>(codebook, frag, cbh);
    quantize_kernel<<<(M_ROWS + 63) / 64, 256, 0, stream>>>(
        x, conv_w, conv_b, codebook, frag, cbh, z_e, z_q, idxs);
    decode_kernel<<<1024, 128, 0, stream>>>(z_q, tconv_w, tconv_b, x_rec);
}

// Round 10
// 119.199 us; speedup vs baseline: 1.2325x; 1.0083x over previous
//
#include <hip/hip_runtime.h>
#include <stdint.h>

// Problem constants
#define N_B   32
#define C_INN 8
#define L_IN  4096
#define C_LAT 64
#define K_EMB 512
#define E_DIM 64
#define L_OUT 2049                 // (4096 + 2*2 - 4)/2 + 1
#define M_ROWS (N_B * L_OUT)       // 65568

// d_out layout (flat float32, reference return order)
#define SZ_XREC (N_B * C_INN * L_IN)     // 1048576
#define SZ_ZE   (N_B * C_LAT * L_OUT)    // 4196352
#define OFF_XREC 0
#define OFF_ZE   (SZ_XREC)
#define OFF_ZQ   (OFF_ZE + SZ_ZE)
#define OFF_IDX  (OFF_ZQ + SZ_ZE)

typedef short short8 __attribute__((ext_vector_type(8)));
typedef float f32x4  __attribute__((ext_vector_type(4)));

__device__ __forceinline__ unsigned short rne16(float f) {
    unsigned u = __float_as_uint(f);
    return (unsigned short)((u + 0x7FFFu + ((u >> 16) & 1u)) >> 16);
}
__device__ __forceinline__ float frombits16(unsigned short h) {
    return __uint_as_float(((unsigned)h) << 16);
}
// order-preserving float->u32 (monotone for all finite values)
__device__ __forceinline__ unsigned orderbits(float f) {
    unsigned u = __float_as_uint(f);
    return u ^ ((unsigned)((int)u >> 31) | 0x80000000u);
}

// ---------------------------------------------------------------------------
// Prep: (a) swizzle codebook into MFMA B-fragment order, split bf16 hi/lo;
// (b) 0.5*||c||^2 per code (same float4 summation order everywhere).
// B8 layout (short8 units): idx = ntile*256 + ks*128 + hl*64 + lane.
// ---------------------------------------------------------------------------
__global__ __launch_bounds__(256) void prep_kernel(
    const float* __restrict__ cb, unsigned short* __restrict__ frag,
    float* __restrict__ cbh)
{
    const int ntile = blockIdx.x;        // 0..31
    const int t     = threadIdx.x;
    const int lane  = t & 63;
    const int ks    = (t >> 6) & 1;
    const int h     = t >> 7;            // 0 = hi, 1 = lo
    const int code  = ntile * 16 + (lane & 15);
    const int k0    = ks * 32 + (lane >> 4) * 8;

    const float* src = cb + (size_t)code * E_DIM + k0;
    unsigned short out[8];
#pragma unroll
    for (int j = 0; j < 8; ++j) {
        const float v = src[j];
        const unsigned short hb = rne16(v);
        out[j] = h ? rne16(v - frombits16(hb)) : hb;
    }
    short8 v8;
#pragma unroll
    for (int j = 0; j < 8; ++j) v8[j] = (short)out[j];
    short8* dst = (short8*)(frag + (((size_t)(ntile * 2 + ks) * 2 + h) * 512 + lane * 8));
    *dst = v8;

    if (t < 16) {
        const int c2 = ntile * 16 + t;
        const float4* cp = (const float4*)(cb + (size_t)c2 * E_DIM);
        float s = 0.0f;
#pragma unroll
        for (int d = 0; d < E_DIM / 4; ++d) {
            float4 v = cp[d];
            s += v.x * v.x + v.y * v.y + v.z * v.z + v.w * v.w;
        }
        cbh[c2] = 0.5f * s;
    }
}

// ---------------------------------------------------------------------------
// Fused encode+quantize+decode, round 19 = R9 quantize (session best, 44us,
// scalarized via wb=readfirstlane) + R8's fused-decode epilogue with the
// uniformity bug FIXED:
//  - R8 failure cause: co0 = wave*2 not provably uniform -> 512 per-lane
//    VMEM weight loads in the epilogue (+24us). R9 proved readfirstlane
//    converts exactly this class into s_loads (-8us in encode).
//  - Here: co0 = wb*2 (SGPR) -> tconv_w reads are s_load_dwordx8 per ci;
//    epilogue vector cost = 128 ds_read + 512 fma ~ 2-3us.
//  - Deletes the 10us decode kernel + launch gap; tiny fixup covers
//    block-boundary rows (r = 64b+63) from global z_q afterward.
//  - s_cand dead after compact scan -> reused as s_zq[64][69] LDS cache.
//  - Edge audit: tt==2048 rows excluded (no output col); last block's
//    active rows 0..30 have active row+1; fixup rows all < M_ROWS.
// Tripwire: quantize > 60us or WRITE >> 41 MB -> uniformity/spill failed.
// ---------------------------------------------------------------------------
__global__ __launch_bounds__(256, 3) void quantize_kernel(
    const float* __restrict__ x, const float* __restrict__ conv_w,
    const float* __restrict__ conv_b, const float* __restrict__ cb,
    const unsigned short* __restrict__ frag, const float* __restrict__ cbh_ws,
    const float* __restrict__ tconv_w, const float* __restrict__ tconv_b,
    float* __restrict__ z_e, float* __restrict__ z_q,
    float* __restrict__ idx_out, float* __restrict__ x_rec)
{
    __shared__ float s_z[E_DIM][66];         // [chan][row] pad2   (16.9 KB)
    __shared__ float s_cbh[K_EMB];           //                    (2 KB)
    __shared__ unsigned s_cand[64][69];      // 64 slots, odd stride (17.7 KB)
    __shared__ float s_pn[64][4];            // per-(row,wave) norm partials
    __shared__ float s_znorm[64];            // 0.5||z||^2 + 1
    __shared__ unsigned s_mstar[64];         // trunc approx-min bits
    __shared__ unsigned long long s_final[64];
    __shared__ unsigned s_list[256];         // compact rescore list (1 KB)
    __shared__ int s_cnt;

    const int tid  = threadIdx.x;
    const int wave = tid >> 6;
    const int lane = tid & 63;
    const int wb   = __builtin_amdgcn_readfirstlane(wave); // provably uniform
    const int p    = wb >> 1;                // rows 32p..32p+31
    const int h    = wb & 1;                 // tiles h*16..h*16+15

    s_cbh[tid]       = cbh_ws[tid];
    s_cbh[tid + 256] = cbh_ws[tid + 256];
    if (tid < 64) s_final[tid] = ~0ULL;
    if (tid == 0) s_cnt = 0;

    // ---- Phase 1: encode my row's 16 channels (row = lane, chans wb*16+j) ----
    const int  row    = lane;
    const int  r      = blockIdx.x * 64 + row;
    const bool active = (r < M_ROWS);
    const unsigned rr = active ? (unsigned)r : 0u;
    const unsigned n  = rr / 2049u;
    const unsigned tt = rr - n * 2049u;

    {
        const float* xrow = x + (size_t)n * (C_INN * L_IN);
        float xv[C_INN][4];
        const bool fast = (tt >= 1 && tt <= 2047);
        if (fast) {
#pragma unroll
            for (int ci = 0; ci < C_INN; ++ci) {
                float4 v = *(const float4*)(xrow + ci * L_IN + (2 * (int)tt - 2));
                xv[ci][0] = v.x; xv[ci][1] = v.y; xv[ci][2] = v.z; xv[ci][3] = v.w;
            }
        } else {
#pragma unroll
            for (int ci = 0; ci < C_INN; ++ci) {
#pragma unroll
                for (int k = 0; k < 4; ++k) {
                    int xi = 2 * (int)tt - 2 + k;
                    int xc = min(max(xi, 0), L_IN - 1);
                    float v = xrow[ci * L_IN + xc];
                    xv[ci][k] = (xi >= 0 && xi < L_IN) ? v : 0.0f;
                }
            }
        }
        float* zcol = z_e + (size_t)n * (C_LAT * L_OUT) + tt;
        float pn = 0.0f;
#pragma unroll
        for (int j = 0; j < 16; ++j) {
            const int c = wb * 16 + j;               // SGPR-uniform channel
            float a = conv_b[c];                     // s_load
#pragma unroll
            for (int ci = 0; ci < C_INN; ++ci) {
                const float* wp = conv_w + (c * C_INN + ci) * 4;  // s_load
#pragma unroll
                for (int k = 0; k < 4; ++k) a += xv[ci][k] * wp[k];
            }
            pn += a * a;
            s_z[c][row] = a;
            if (active) zcol[(size_t)c * L_OUT] = a;
        }
        s_pn[row][wb] = pn;
    }
    __syncthreads();

    // ---- row norms from 4 partials (one thread per row) ----
    if (tid < 64) {
        s_znorm[tid] = 0.5f * (s_pn[tid][0] + s_pn[tid][1] +
                               s_pn[tid][2] + s_pn[tid][3]) + 1.0f;
    }

    const int m = lane & 15, q = lane >> 4;
    short8 Ah[2][2], Al[2][2];               // [strip][ks], A = -z
#pragma unroll
    for (int st = 0; st < 2; ++st) {
        const int arow = p * 32 + st * 16 + m;
#pragma unroll
        for (int ks = 0; ks < 2; ++ks) {
#pragma unroll
            for (int j = 0; j < 8; ++j) {
                const float v = -s_z[ks * 32 + q * 8 + j][arow];
                const unsigned short hb = rne16(v);
                Ah[st][ks][j] = (short)hb;
                Al[st][ks][j] = (short)rne16(v - frombits16(hb));
            }
        }
    }
    __syncthreads();

    float Kn[2][4];
#pragma unroll
    for (int st = 0; st < 2; ++st)
#pragma unroll
        for (int r4 = 0; r4 < 4; ++r4)
            Kn[st][r4] = s_znorm[p * 32 + st * 16 + q * 4 + r4];

    // ---- screen: 16 tiles of half h, register prefetch depth 1 ----
    unsigned ca[2][4], cb2[2][4];
#pragma unroll
    for (int st = 0; st < 2; ++st)
#pragma unroll
        for (int r4 = 0; r4 < 4; ++r4) { ca[st][r4] = 0xFFFFFFFFu; cb2[st][r4] = 0xFFFFFFFFu; }

    const short8* B8 = (const short8*)frag;
    short8 Bc[4], Bn[4];
    {
        const int base = (h * 16) * 256 + lane;      // scalar base + lane
#pragma unroll
        for (int v = 0; v < 4; ++v) Bc[v] = B8[base + v * 64];
    }

    for (int t = 0; t < 16; ++t) {
        if (t < 15) {
            const int base = (h * 16 + t + 1) * 256 + lane;
#pragma unroll
            for (int v = 0; v < 4; ++v) Bn[v] = B8[base + v * 64];
        }
        const int code = (h * 16 + t) * 16 + m;
        const float chv = s_cbh[code];

        f32x4 accA = {chv + Kn[0][0], chv + Kn[0][1], chv + Kn[0][2], chv + Kn[0][3]};
        f32x4 accB = {chv + Kn[1][0], chv + Kn[1][1], chv + Kn[1][2], chv + Kn[1][3]};
        accA = __builtin_amdgcn_mfma_f32_16x16x32_bf16(Ah[0][0], Bc[0], accA, 0, 0, 0);
        accB = __builtin_amdgcn_mfma_f32_16x16x32_bf16(Ah[1][0], Bc[0], accB, 0, 0, 0);
        accA = __builtin_amdgcn_mfma_f32_16x16x32_bf16(Ah[0][0], Bc[1], accA, 0, 0, 0);
        accB = __builtin_amdgcn_mfma_f32_16x16x32_bf16(Ah[1][0], Bc[1], accB, 0, 0, 0);
        accA = __builtin_amdgcn_mfma_f32_16x16x32_bf16(Al[0][0], Bc[0], accA, 0, 0, 0);
        accB = __builtin_amdgcn_mfma_f32_16x16x32_bf16(Al[1][0], Bc[0], accB, 0, 0, 0);
        accA = __builtin_amdgcn_mfma_f32_16x16x32_bf16(Ah[0][1], Bc[2], accA, 0, 0, 0);
        accB = __builtin_amdgcn_mfma_f32_16x16x32_bf16(Ah[1][1], Bc[2], accB, 0, 0, 0);
        accA = __builtin_amdgcn_mfma_f32_16x16x32_bf16(Ah[0][1], Bc[3], accA, 0, 0, 0);
        accB = __builtin_amdgcn_mfma_f32_16x16x32_bf16(Ah[1][1], Bc[3], accB, 0, 0, 0);
        accA = __builtin_amdgcn_mfma_f32_16x16x32_bf16(Al[0][1], Bc[2], accA, 0, 0, 0);
        accB = __builtin_amdgcn_mfma_f32_16x16x32_bf16(Al[1][1], Bc[2], accB, 0, 0, 0);

#pragma unroll
        for (int st = 0; st < 2; ++st) {
            const f32x4 acc = st ? accB : accA;
#pragma unroll
            for (int r4 = 0; r4 < 4; ++r4) {
                const unsigned xx = (__float_as_uint(acc[r4]) & 0xFFFFFFF0u) | (unsigned)t;
                const unsigned mx = max(ca[st][r4], xx);
                ca[st][r4]  = min(ca[st][r4], xx);
                cb2[st][r4] = min(cb2[st][r4], mx);
            }
        }
#pragma unroll
        for (int v = 0; v < 4; ++v) Bc[v] = Bn[v];
    }

    // deposit: row = 32p + 16st + 4q + r4, slots h*32 + 2m (+1)
#pragma unroll
    for (int st = 0; st < 2; ++st)
#pragma unroll
        for (int r4 = 0; r4 < 4; ++r4) {
            const int rw = p * 32 + st * 16 + q * 4 + r4;
            s_cand[rw][h * 32 + 2 * m + 0] = ca[st][r4];
            s_cand[rw][h * 32 + 2 * m + 1] = cb2[st][r4];
        }
    __syncthreads();

    // per-row approx min over the 64 candidate slots
    if (tid < 64) {
        unsigned mn = 0xFFFFFFFFu;
#pragma unroll 8
        for (int i = 0; i < 64; ++i) mn = min(mn, s_cand[tid][i]);
        s_mstar[tid] = mn & 0xFFFFFFF0u;
    }
    __syncthreads();

    // ---- compact: scan candidates within m* + eps into s_list (cheap) ----
    {
        const int rw  = tid >> 2;                    // 4 threads per row
        const float thr = __uint_as_float(s_mstar[rw]) + 0.02f;
#pragma unroll
        for (int j = 0; j < 16; ++j) {
            const int sl = (tid & 3) * 16 + j;       // 0..63
            const unsigned cand = s_cand[rw][sl];
            const float fd = __uint_as_float(cand & 0xFFFFFFF0u);
            if (fd <= thr) {
                // slot -> (half = sl>>5, class m = (sl>>1)&15), tile = cand&15
                const unsigned code =
                    (((unsigned)(sl >> 5) * 16u + (cand & 15u)) * 16u) +
                    (unsigned)((sl >> 1) & 15);
                const int pos = atomicAdd(&s_cnt, 1);
                if (pos < 256) {
                    s_list[pos] = ((unsigned)rw << 9) | code;
                } else {
                    // overflow fallback (practically never): inline exact path
                    const float4* c4 = (const float4*)(cb + (size_t)code * E_DIM);
                    float dot = 0.0f;
#pragma unroll
                    for (int d4 = 0; d4 < 16; ++d4) {
                        const float4 cv = c4[d4];
                        dot += s_z[d4 * 4 + 0][rw] * cv.x +
                               s_z[d4 * 4 + 1][rw] * cv.y +
                               s_z[d4 * 4 + 2][rw] * cv.z +
                               s_z[d4 * 4 + 3][rw] * cv.w;
                    }
                    const float mex = s_cbh[code] - dot;
                    const unsigned long long px =
                        ((unsigned long long)orderbits(mex) << 32) | code;
                    atomicMin(&s_final[rw], px);
                }
            }
        }
    }
    __syncthreads();

    // ---- dense rescore: one entry per lane, single pass ----
    {
        const int nk = min(s_cnt, 256);
        for (int e = tid; e < nk; e += 256) {
            const unsigned ent = s_list[e];
            const int rw = (int)(ent >> 9);
            const unsigned code = ent & 511u;
            const float4* c4 = (const float4*)(cb + (size_t)code * E_DIM);
            float dot = 0.0f;
#pragma unroll
            for (int d4 = 0; d4 < 16; ++d4) {
                const float4 cv = c4[d4];
                dot += s_z[d4 * 4 + 0][rw] * cv.x +
                       s_z[d4 * 4 + 1][rw] * cv.y +
                       s_z[d4 * 4 + 2][rw] * cv.z +
                       s_z[d4 * 4 + 3][rw] * cv.w;
            }
            const float mex = s_cbh[code] - dot;
            const unsigned long long px =
                ((unsigned long long)orderbits(mex) << 32) | code;
            atomicMin(&s_final[rw], px);
        }
    }
    __syncthreads();

    // ---- Phase A: gather selected codebook row; stash into LDS for decode.
    // s_cand is dead past this point -> reuse as float z_q cache [64][69].
    float* s_zq = (float*)&s_cand[0][0];     // stride 69
    unsigned fk = 0;
    float4 csel4[4];
    if (active) {
        fk = (unsigned)s_final[row];
        const float4* csel = (const float4*)(cb + (size_t)fk * E_DIM);
#pragma unroll
        for (int j4 = 0; j4 < 4; ++j4) csel4[j4] = csel[wb * 4 + j4];
#pragma unroll
        for (int j4 = 0; j4 < 4; ++j4) {
            const int c = wb * 16 + j4 * 4;          // chans wb*16+4j4..+3
            s_zq[row * 69 + c + 0] = csel4[j4].x;
            s_zq[row * 69 + c + 1] = csel4[j4].y;
            s_zq[row * 69 + c + 2] = csel4[j4].z;
            s_zq[row * 69 + c + 3] = csel4[j4].w;
        }
    }
    __syncthreads();   // only LDS writes pending -> cheap drain

    // ---- Phase B: all global stores + fused decode; no barrier after ----
    if (active) {
        float* zq = z_q + (size_t)n * (C_LAT * L_OUT) + tt;
#pragma unroll
        for (int j4 = 0; j4 < 4; ++j4) {
            const int c = wb * 16 + j4 * 4;
            zq[(size_t)(c + 0) * L_OUT] = csel4[j4].x;
            zq[(size_t)(c + 1) * L_OUT] = csel4[j4].y;
            zq[(size_t)(c + 2) * L_OUT] = csel4[j4].z;
            zq[(size_t)(c + 3) * L_OUT] = csel4[j4].w;
        }
        if (tid < 64) idx_out[r] = (float)fk;

        // fused ConvTranspose for s = tt; this wave computes co = wb*2, +1.
        // Needs row+1's z_q: in-block only for row < 63 (row 63 -> fixup).
        if (row < 63 && tt < 2048) {
            const int co0 = wb * 2;                  // SGPR-uniform!
            float e0 = tconv_b[co0],     o0 = e0;    // s_load
            float e1 = tconv_b[co0 + 1], o1 = e1;
            const float* z0p = s_zq + row * 69;
            const float* z1p = s_zq + (row + 1) * 69;
#pragma unroll 8
            for (int ci = 0; ci < C_LAT; ++ci) {
                const float z0 = z0p[ci];
                const float z1 = z1p[ci];
                const float* wp = tconv_w + (ci * C_INN + co0) * 4;  // s_load
                e0 += z0 * wp[2] + z1 * wp[0];
                o0 += z0 * wp[3] + z1 * wp[1];
                e1 += z0 * wp[6] + z1 * wp[4];
                o1 += z0 * wp[7] + z1 * wp[5];
            }
            float* xr0 = x_rec + ((size_t)(n * C_INN + co0)) * L_IN + 2 * tt;
            float* xr1 = x_rec + ((size_t)(n * C_INN + co0 + 1)) * L_IN + 2 * tt;
            *(float2*)xr0 = make_float2(e0, o0);
            *(float2*)xr1 = make_float2(e1, o1);
        }
    }
}

// ---------------------------------------------------------------------------
// Boundary fixup: output columns s = tt for rows r = 64b + 63 (the in-block
// fused decode cannot see row+1 across blocks). 1024 boundaries; all
// r < M_ROWS; skip tt == 2048 (no output column). Same per-ci fma order.
// Runs after quantize completes -> all z_q visible (no ordering assumption).
// ---------------------------------------------------------------------------
__global__ __launch_bounds__(64) void fixup_kernel(
    const float* __restrict__ zq, const float* __restrict__ w,
    const float* __restrict__ b, float* __restrict__ xr)
{
    const int bd = blockIdx.x;              // 0..1023
    const int r  = bd * 64 + 63;
    const unsigned n  = (unsigned)r / 2049u;
    const unsigned tt = (unsigned)r - n * 2049u;
    if (tt >= 2048) return;                 // block-uniform exit

    __shared__ float zz[2][64];
    const int ci = threadIdx.x;             // 0..63
    const float* zp = zq + (size_t)n * (C_LAT * L_OUT) + (size_t)ci * L_OUT + tt;
    zz[0][ci] = zp[0];
    zz[1][ci] = zp[1];
    __syncthreads();

    if (ci < 16) {
        const int co = ci >> 1, par = ci & 1;
        float a = b[co];
        for (int c = 0; c < C_LAT; ++c) {
            const float* wp = w + (c * C_INN + co) * 4;
            a += zz[0][c] * wp[2 + par] + zz[1][c] * wp[0 + par];
        }
        xr[((size_t)(n * C_INN + co)) * L_IN + 2 * tt + par] = a;
    }
}

// ---------------------------------------------------------------------------
extern "C" void kernel_launch(void* const* d_in, const int* in_sizes, int n_in,
                              void* d_out, int out_size, void* d_ws, size_t ws_size,
                              hipStream_t stream) {
    const float* x        = (const float*)d_in[0];
    const float* conv_w   = (const float*)d_in[1];
    const float* conv_b   = (const float*)d_in[2];
    const float* codebook = (const float*)d_in[3];
    const float* tconv_w  = (const float*)d_in[4];
    const float* tconv_b  = (const float*)d_in[5];

    float* out   = (float*)d_out;
    float* x_rec = out + OFF_XREC;
    float* z_e   = out + OFF_ZE;
    float* z_q   = out + OFF_ZQ;
    float* idxs  = out + OFF_IDX;

    unsigned short* frag = (unsigned short*)d_ws;        // 131072 B
    float*          cbh  = (float*)(frag + 65536);       // + 2048 B

    prep_kernel<<<32, 256, 0, stream>>>(codebook, frag, cbh);
    quantize_kernel<<<(M_ROWS + 63) / 64, 256, 0, stream>>>(
        x, conv_w, conv_b, codebook, frag, cbh, tconv_w, tconv_b,
        z_e, z_q, idxs, x_rec);
    fixup_kernel<<<1024, 64, 0, stream>>>(z_q, tconv_w, tconv_b, x_rec);
}

// Round 11
// 118.668 us; speedup vs baseline: 1.2380x; 1.0045x over previous
//
#include <hip/hip_runtime.h>
#include <stdint.h>

// Problem constants
#define N_B   32
#define C_INN 8
#define L_IN  4096
#define C_LAT 64
#define K_EMB 512
#define E_DIM 64
#define L_OUT 2049                 // (4096 + 2*2 - 4)/2 + 1
#define M_ROWS (N_B * L_OUT)       // 65568

// d_out layout (flat float32, reference return order)
#define SZ_XREC (N_B * C_INN * L_IN)     // 1048576
#define SZ_ZE   (N_B * C_LAT * L_OUT)    // 4196352
#define OFF_XREC 0
#define OFF_ZE   (SZ_XREC)
#define OFF_ZQ   (OFF_ZE + SZ_ZE)
#define OFF_IDX  (OFF_ZQ + SZ_ZE)

typedef short short8 __attribute__((ext_vector_type(8)));
typedef float f32x4  __attribute__((ext_vector_type(4)));

__device__ __forceinline__ unsigned short rne16(float f) {
    unsigned u = __float_as_uint(f);
    return (unsigned short)((u + 0x7FFFu + ((u >> 16) & 1u)) >> 16);
}
__device__ __forceinline__ float frombits16(unsigned short h) {
    return __uint_as_float(((unsigned)h) << 16);
}
// order-preserving float->u32 (monotone for all finite values)
__device__ __forceinline__ unsigned orderbits(float f) {
    unsigned u = __float_as_uint(f);
    return u ^ ((unsigned)((int)u >> 31) | 0x80000000u);
}

// ---------------------------------------------------------------------------
// Prep: (a) swizzle codebook into MFMA B-fragment order, split bf16 hi/lo;
// (b) 0.5*||c||^2 per code (same float4 summation order everywhere).
// B8 layout (short8 units): idx = ntile*256 + ks*128 + hl*64 + lane.
// ---------------------------------------------------------------------------
__global__ __launch_bounds__(256) void prep_kernel(
    const float* __restrict__ cb, unsigned short* __restrict__ frag,
    float* __restrict__ cbh)
{
    const int ntile = blockIdx.x;        // 0..31
    const int t     = threadIdx.x;
    const int lane  = t & 63;
    const int ks    = (t >> 6) & 1;
    const int h     = t >> 7;            // 0 = hi, 1 = lo
    const int code  = ntile * 16 + (lane & 15);
    const int k0    = ks * 32 + (lane >> 4) * 8;

    const float* src = cb + (size_t)code * E_DIM + k0;
    unsigned short out[8];
#pragma unroll
    for (int j = 0; j < 8; ++j) {
        const float v = src[j];
        const unsigned short hb = rne16(v);
        out[j] = h ? rne16(v - frombits16(hb)) : hb;
    }
    short8 v8;
#pragma unroll
    for (int j = 0; j < 8; ++j) v8[j] = (short)out[j];
    short8* dst = (short8*)(frag + (((size_t)(ntile * 2 + ks) * 2 + h) * 512 + lane * 8));
    *dst = v8;

    if (t < 16) {
        const int c2 = ntile * 16 + t;
        const float4* cp = (const float4*)(cb + (size_t)c2 * E_DIM);
        float s = 0.0f;
#pragma unroll
        for (int d = 0; d < E_DIM / 4; ++d) {
            float4 v = cp[d];
            s += v.x * v.x + v.y * v.y + v.z * v.z + v.w * v.w;
        }
        cbh[c2] = 0.5f * s;
    }
}

// ---------------------------------------------------------------------------
// Fused encode+quantize+decode, round 20 = R10 (best, 119.2us) + one
// surgical phase-merge:
//  - min-scan phase DELETED: mstar = min over the 64 slots = min over the
//    ca values alone (cb2 >= ca by construction). Each thread atomicMins
//    its 8 register ca values into s_mstar[rw] during deposit (ds_min_u32,
//    parallel, 32 atomics/address) -> one fewer barrier + the 700cy serial
//    64-reads-per-row scan (3/4 of block idle) is gone.
//  - bit-exact: min-then-mask == mask-then-min here (low 4 tile bits only
//    break ties among equal masked values); thr, candidate set, rescore
//    unchanged.
// R10 ledger: fused decode verified correct + no spill (WRITE 40.85 MB
// exactly = x_rec absorption; VGPR 64). R10's +16us quantize vs R9 is
// part slow chip (unprofiled dispatch also 59us; R6 showed +-12% clock),
// part Phase-A gather latency on the barrier path. Structure kept: decode
// kernel + launch gap provably eliminated.
// ---------------------------------------------------------------------------
__global__ __launch_bounds__(256, 3) void quantize_kernel(
    const float* __restrict__ x, const float* __restrict__ conv_w,
    const float* __restrict__ conv_b, const float* __restrict__ cb,
    const unsigned short* __restrict__ frag, const float* __restrict__ cbh_ws,
    const float* __restrict__ tconv_w, const float* __restrict__ tconv_b,
    float* __restrict__ z_e, float* __restrict__ z_q,
    float* __restrict__ idx_out, float* __restrict__ x_rec)
{
    __shared__ float s_z[E_DIM][66];         // [chan][row] pad2   (16.9 KB)
    __shared__ float s_cbh[K_EMB];           //                    (2 KB)
    __shared__ unsigned s_cand[64][69];      // 64 slots, odd stride (17.7 KB)
    __shared__ float s_pn[64][4];            // per-(row,wave) norm partials
    __shared__ float s_znorm[64];            // 0.5||z||^2 + 1
    __shared__ unsigned s_mstar[64];         // raw approx-min bits (atomic)
    __shared__ unsigned long long s_final[64];
    __shared__ unsigned s_list[256];         // compact rescore list (1 KB)
    __shared__ int s_cnt;

    const int tid  = threadIdx.x;
    const int wave = tid >> 6;
    const int lane = tid & 63;
    const int wb   = __builtin_amdgcn_readfirstlane(wave); // provably uniform
    const int p    = wb >> 1;                // rows 32p..32p+31
    const int h    = wb & 1;                 // tiles h*16..h*16+15

    s_cbh[tid]       = cbh_ws[tid];
    s_cbh[tid + 256] = cbh_ws[tid + 256];
    if (tid < 64) { s_final[tid] = ~0ULL; s_mstar[tid] = 0xFFFFFFFFu; }
    if (tid == 0) s_cnt = 0;

    // ---- Phase 1: encode my row's 16 channels (row = lane, chans wb*16+j) ----
    const int  row    = lane;
    const int  r      = blockIdx.x * 64 + row;
    const bool active = (r < M_ROWS);
    const unsigned rr = active ? (unsigned)r : 0u;
    const unsigned n  = rr / 2049u;
    const unsigned tt = rr - n * 2049u;

    {
        const float* xrow = x + (size_t)n * (C_INN * L_IN);
        float xv[C_INN][4];
        const bool fast = (tt >= 1 && tt <= 2047);
        if (fast) {
#pragma unroll
            for (int ci = 0; ci < C_INN; ++ci) {
                float4 v = *(const float4*)(xrow + ci * L_IN + (2 * (int)tt - 2));
                xv[ci][0] = v.x; xv[ci][1] = v.y; xv[ci][2] = v.z; xv[ci][3] = v.w;
            }
        } else {
#pragma unroll
            for (int ci = 0; ci < C_INN; ++ci) {
#pragma unroll
                for (int k = 0; k < 4; ++k) {
                    int xi = 2 * (int)tt - 2 + k;
                    int xc = min(max(xi, 0), L_IN - 1);
                    float v = xrow[ci * L_IN + xc];
                    xv[ci][k] = (xi >= 0 && xi < L_IN) ? v : 0.0f;
                }
            }
        }
        float* zcol = z_e + (size_t)n * (C_LAT * L_OUT) + tt;
        float pn = 0.0f;
#pragma unroll
        for (int j = 0; j < 16; ++j) {
            const int c = wb * 16 + j;               // SGPR-uniform channel
            float a = conv_b[c];                     // s_load
#pragma unroll
            for (int ci = 0; ci < C_INN; ++ci) {
                const float* wp = conv_w + (c * C_INN + ci) * 4;  // s_load
#pragma unroll
                for (int k = 0; k < 4; ++k) a += xv[ci][k] * wp[k];
            }
            pn += a * a;
            s_z[c][row] = a;
            if (active) zcol[(size_t)c * L_OUT] = a;
        }
        s_pn[row][wb] = pn;
    }
    __syncthreads();

    // ---- row norms from 4 partials (one thread per row) ----
    if (tid < 64) {
        s_znorm[tid] = 0.5f * (s_pn[tid][0] + s_pn[tid][1] +
                               s_pn[tid][2] + s_pn[tid][3]) + 1.0f;
    }

    const int m = lane & 15, q = lane >> 4;
    short8 Ah[2][2], Al[2][2];               // [strip][ks], A = -z
#pragma unroll
    for (int st = 0; st < 2; ++st) {
        const int arow = p * 32 + st * 16 + m;
#pragma unroll
        for (int ks = 0; ks < 2; ++ks) {
#pragma unroll
            for (int j = 0; j < 8; ++j) {
                const float v = -s_z[ks * 32 + q * 8 + j][arow];
                const unsigned short hb = rne16(v);
                Ah[st][ks][j] = (short)hb;
                Al[st][ks][j] = (short)rne16(v - frombits16(hb));
            }
        }
    }
    __syncthreads();

    float Kn[2][4];
#pragma unroll
    for (int st = 0; st < 2; ++st)
#pragma unroll
        for (int r4 = 0; r4 < 4; ++r4)
            Kn[st][r4] = s_znorm[p * 32 + st * 16 + q * 4 + r4];

    // ---- screen: 16 tiles of half h, register prefetch depth 1 ----
    unsigned ca[2][4], cb2[2][4];
#pragma unroll
    for (int st = 0; st < 2; ++st)
#pragma unroll
        for (int r4 = 0; r4 < 4; ++r4) { ca[st][r4] = 0xFFFFFFFFu; cb2[st][r4] = 0xFFFFFFFFu; }

    const short8* B8 = (const short8*)frag;
    short8 Bc[4], Bn[4];
    {
        const int base = (h * 16) * 256 + lane;      // scalar base + lane
#pragma unroll
        for (int v = 0; v < 4; ++v) Bc[v] = B8[base + v * 64];
    }

    for (int t = 0; t < 16; ++t) {
        if (t < 15) {
            const int base = (h * 16 + t + 1) * 256 + lane;
#pragma unroll
            for (int v = 0; v < 4; ++v) Bn[v] = B8[base + v * 64];
        }
        const int code = (h * 16 + t) * 16 + m;
        const float chv = s_cbh[code];

        f32x4 accA = {chv + Kn[0][0], chv + Kn[0][1], chv + Kn[0][2], chv + Kn[0][3]};
        f32x4 accB = {chv + Kn[1][0], chv + Kn[1][1], chv + Kn[1][2], chv + Kn[1][3]};
        accA = __builtin_amdgcn_mfma_f32_16x16x32_bf16(Ah[0][0], Bc[0], accA, 0, 0, 0);
        accB = __builtin_amdgcn_mfma_f32_16x16x32_bf16(Ah[1][0], Bc[0], accB, 0, 0, 0);
        accA = __builtin_amdgcn_mfma_f32_16x16x32_bf16(Ah[0][0], Bc[1], accA, 0, 0, 0);
        accB = __builtin_amdgcn_mfma_f32_16x16x32_bf16(Ah[1][0], Bc[1], accB, 0, 0, 0);
        accA = __builtin_amdgcn_mfma_f32_16x16x32_bf16(Al[0][0], Bc[0], accA, 0, 0, 0);
        accB = __builtin_amdgcn_mfma_f32_16x16x32_bf16(Al[1][0], Bc[0], accB, 0, 0, 0);
        accA = __builtin_amdgcn_mfma_f32_16x16x32_bf16(Ah[0][1], Bc[2], accA, 0, 0, 0);
        accB = __builtin_amdgcn_mfma_f32_16x16x32_bf16(Ah[1][1], Bc[2], accB, 0, 0, 0);
        accA = __builtin_amdgcn_mfma_f32_16x16x32_bf16(Ah[0][1], Bc[3], accA, 0, 0, 0);
        accB = __builtin_amdgcn_mfma_f32_16x16x32_bf16(Ah[1][1], Bc[3], accB, 0, 0, 0);
        accA = __builtin_amdgcn_mfma_f32_16x16x32_bf16(Al[0][1], Bc[2], accA, 0, 0, 0);
        accB = __builtin_amdgcn_mfma_f32_16x16x32_bf16(Al[1][1], Bc[2], accB, 0, 0, 0);

#pragma unroll
        for (int st = 0; st < 2; ++st) {
            const f32x4 acc = st ? accB : accA;
#pragma unroll
            for (int r4 = 0; r4 < 4; ++r4) {
                const unsigned xx = (__float_as_uint(acc[r4]) & 0xFFFFFFF0u) | (unsigned)t;
                const unsigned mx = max(ca[st][r4], xx);
                ca[st][r4]  = min(ca[st][r4], xx);
                cb2[st][r4] = min(cb2[st][r4], mx);
            }
        }
#pragma unroll
        for (int v = 0; v < 4; ++v) Bc[v] = Bn[v];
    }

    // deposit + fused approx-min: row = 32p + 16st + 4q + r4, slots h*32+2m.
    // mstar needs only the ca values (cb2 >= ca); ds_min_u32 is parallel.
#pragma unroll
    for (int st = 0; st < 2; ++st)
#pragma unroll
        for (int r4 = 0; r4 < 4; ++r4) {
            const int rw = p * 32 + st * 16 + q * 4 + r4;
            s_cand[rw][h * 32 + 2 * m + 0] = ca[st][r4];
            s_cand[rw][h * 32 + 2 * m + 1] = cb2[st][r4];
            atomicMin(&s_mstar[rw], ca[st][r4]);
        }
    __syncthreads();

    // ---- compact: scan candidates within m* + eps into s_list (cheap) ----
    {
        const int rw  = tid >> 2;                    // 4 threads per row
        const float thr =
            __uint_as_float(s_mstar[rw] & 0xFFFFFFF0u) + 0.02f;
#pragma unroll
        for (int j = 0; j < 16; ++j) {
            const int sl = (tid & 3) * 16 + j;       // 0..63
            const unsigned cand = s_cand[rw][sl];
            const float fd = __uint_as_float(cand & 0xFFFFFFF0u);
            if (fd <= thr) {
                // slot -> (half = sl>>5, class m = (sl>>1)&15), tile = cand&15
                const unsigned code =
                    (((unsigned)(sl >> 5) * 16u + (cand & 15u)) * 16u) +
                    (unsigned)((sl >> 1) & 15);
                const int pos = atomicAdd(&s_cnt, 1);
                if (pos < 256) {
                    s_list[pos] = ((unsigned)rw << 9) | code;
                } else {
                    // overflow fallback (practically never): inline exact path
                    const float4* c4 = (const float4*)(cb + (size_t)code * E_DIM);
                    float dot = 0.0f;
#pragma unroll
                    for (int d4 = 0; d4 < 16; ++d4) {
                        const float4 cv = c4[d4];
                        dot += s_z[d4 * 4 + 0][rw] * cv.x +
                               s_z[d4 * 4 + 1][rw] * cv.y +
                               s_z[d4 * 4 + 2][rw] * cv.z +
                               s_z[d4 * 4 + 3][rw] * cv.w;
                    }
                    const float mex = s_cbh[code] - dot;
                    const unsigned long long px =
                        ((unsigned long long)orderbits(mex) << 32) | code;
                    atomicMin(&s_final[rw], px);
                }
            }
        }
    }
    __syncthreads();

    // ---- dense rescore: one entry per lane, single pass ----
    {
        const int nk = min(s_cnt, 256);
        for (int e = tid; e < nk; e += 256) {
            const unsigned ent = s_list[e];
            const int rw = (int)(ent >> 9);
            const unsigned code = ent & 511u;
            const float4* c4 = (const float4*)(cb + (size_t)code * E_DIM);
            float dot = 0.0f;
#pragma unroll
            for (int d4 = 0; d4 < 16; ++d4) {
                const float4 cv = c4[d4];
                dot += s_z[d4 * 4 + 0][rw] * cv.x +
                       s_z[d4 * 4 + 1][rw] * cv.y +
                       s_z[d4 * 4 + 2][rw] * cv.z +
                       s_z[d4 * 4 + 3][rw] * cv.w;
            }
            const float mex = s_cbh[code] - dot;
            const unsigned long long px =
                ((unsigned long long)orderbits(mex) << 32) | code;
            atomicMin(&s_final[rw], px);
        }
    }
    __syncthreads();

    // ---- Phase A: gather selected codebook row; stash into LDS for decode.
    // s_cand is dead past this point -> reuse as float z_q cache [64][69].
    float* s_zq = (float*)&s_cand[0][0];     // stride 69
    unsigned fk = 0;
    float4 csel4[4];
    if (active) {
        fk = (unsigned)s_final[row];
        const float4* csel = (const float4*)(cb + (size_t)fk * E_DIM);
#pragma unroll
        for (int j4 = 0; j4 < 4; ++j4) csel4[j4] = csel[wb * 4 + j4];
#pragma unroll
        for (int j4 = 0; j4 < 4; ++j4) {
            const int c = wb * 16 + j4 * 4;          // chans wb*16+4j4..+3
            s_zq[row * 69 + c + 0] = csel4[j4].x;
            s_zq[row * 69 + c + 1] = csel4[j4].y;
            s_zq[row * 69 + c + 2] = csel4[j4].z;
            s_zq[row * 69 + c + 3] = csel4[j4].w;
        }
    }
    __syncthreads();   // only LDS writes pending -> cheap drain

    // ---- Phase B: all global stores + fused decode; no barrier after ----
    if (active) {
        float* zq = z_q + (size_t)n * (C_LAT * L_OUT) + tt;
#pragma unroll
        for (int j4 = 0; j4 < 4; ++j4) {
            const int c = wb * 16 + j4 * 4;
            zq[(size_t)(c + 0) * L_OUT] = csel4[j4].x;
            zq[(size_t)(c + 1) * L_OUT] = csel4[j4].y;
            zq[(size_t)(c + 2) * L_OUT] = csel4[j4].z;
            zq[(size_t)(c + 3) * L_OUT] = csel4[j4].w;
        }
        if (tid < 64) idx_out[r] = (float)fk;

        // fused ConvTranspose for s = tt; this wave computes co = wb*2, +1.
        // Needs row+1's z_q: in-block only for row < 63 (row 63 -> fixup).
        if (row < 63 && tt < 2048) {
            const int co0 = wb * 2;                  // SGPR-uniform
            float e0 = tconv_b[co0],     o0 = e0;    // s_load
            float e1 = tconv_b[co0 + 1], o1 = e1;
            const float* z0p = s_zq + row * 69;
            const float* z1p = s_zq + (row + 1) * 69;
#pragma unroll 8
            for (int ci = 0; ci < C_LAT; ++ci) {
                const float z0 = z0p[ci];
                const float z1 = z1p[ci];
                const float* wp = tconv_w + (ci * C_INN + co0) * 4;  // s_load
                e0 += z0 * wp[2] + z1 * wp[0];
                o0 += z0 * wp[3] + z1 * wp[1];
                e1 += z0 * wp[6] + z1 * wp[4];
                o1 += z0 * wp[7] + z1 * wp[5];
            }
            float* xr0 = x_rec + ((size_t)(n * C_INN + co0)) * L_IN + 2 * tt;
            float* xr1 = x_rec + ((size_t)(n * C_INN + co0 + 1)) * L_IN + 2 * tt;
            *(float2*)xr0 = make_float2(e0, o0);
            *(float2*)xr1 = make_float2(e1, o1);
        }
    }
}

// ---------------------------------------------------------------------------
// Boundary fixup: output columns s = tt for rows r = 64b + 63 (the in-block
// fused decode cannot see row+1 across blocks). 1024 boundaries; all
// r < M_ROWS; skip tt == 2048 (no output column). Same per-ci fma order.
// Runs after quantize completes -> all z_q visible (no ordering assumption).
// ---------------------------------------------------------------------------
__global__ __launch_bounds__(64) void fixup_kernel(
    const float* __restrict__ zq, const float* __restrict__ w,
    const float* __restrict__ b, float* __restrict__ xr)
{
    const int bd = blockIdx.x;              // 0..1023
    const int r  = bd * 64 + 63;
    const unsigned n  = (unsigned)r / 2049u;
    const unsigned tt = (unsigned)r - n * 2049u;
    if (tt >= 2048) return;                 // block-uniform exit

    __shared__ float zz[2][64];
    const int ci = threadIdx.x;             // 0..63
    const float* zp = zq + (size_t)n * (C_LAT * L_OUT) + (size_t)ci * L_OUT + tt;
    zz[0][ci] = zp[0];
    zz[1][ci] = zp[1];
    __syncthreads();

    if (ci < 16) {
        const int co = ci >> 1, par = ci & 1;
        float a = b[co];
        for (int c = 0; c < C_LAT; ++c) {
            const float* wp = w + (c * C_INN + co) * 4;
            a += zz[0][c] * wp[2 + par] + zz[1][c] * wp[0 + par];
        }
        xr[((size_t)(n * C_INN + co)) * L_IN + 2 * tt + par] = a;
    }
}

// ---------------------------------------------------------------------------
extern "C" void kernel_launch(void* const* d_in, const int* in_sizes, int n_in,
                              void* d_out, int out_size, void* d_ws, size_t ws_size,
                              hipStream_t stream) {
    const float* x        = (const float*)d_in[0];
    const float* conv_w   = (const float*)d_in[1];
    const float* conv_b   = (const float*)d_in[2];
    const float* codebook = (const float*)d_in[3];
    const float* tconv_w  = (const float*)d_in[4];
    const float* tconv_b  = (const float*)d_in[5];

    float* out   = (float*)d_out;
    float* x_rec = out + OFF_XREC;
    float* z_e   = out + OFF_ZE;
    float* z_q   = out + OFF_ZQ;
    float* idxs  = out + OFF_IDX;

    unsigned short* frag = (unsigned short*)d_ws;        // 131072 B
    float*          cbh  = (float*)(frag + 65536);       // + 2048 B

    prep_kernel<<<32, 256, 0, stream>>>(codebook, frag, cbh);
    quantize_kernel<<<(M_ROWS + 63) / 64, 256, 0, stream>>>(
        x, conv_w, conv_b, codebook, frag, cbh, tconv_w, tconv_b,
        z_e, z_q, idxs, x_rec);
    fixup_kernel<<<1024, 64, 0, stream>>>(z_q, tconv_w, tconv_b, x_rec);
}